// Round 2
// baseline (208.313 us; speedup 1.0000x reference)
//
#include <hip/hip_runtime.h>
#include <math.h>

#define TPB 1024
// per image: 128*128 px * 3 ch = 49152 floats = 12288 float4 = 4 groups * 3072
#define GROUP_STRIDE 3072   // TPB * 3

__device__ __forceinline__ float s2lin(float c) {
    // inverse sRGB gamma; c in [0,1]
    float p = exp2f(log2f((c + 0.055f) * (1.0f / 1.055f)) * 2.4f);
    float l = c * (1.0f / 12.92f);
    return c > 0.04045f ? p : l;
}

__device__ __forceinline__ float labf(float t) {
    // CIE f(); t > eps on the exp2/log2 path so log2f input is positive.
    float p = exp2f(log2f(t) * (1.0f / 3.0f));
    float l = 7.787f * t + (16.0f / 116.0f);
    return t > 0.008856f ? p : l;
}

__device__ __forceinline__ void px(float r, float g, float b,
                                   float& L, float& a01, float& b01) {
    float lr = s2lin(r), lg = s2lin(g), lb = s2lin(b);
    // RGB2XYZ rows pre-divided by D65 white (0.95047, 1.0, 1.08883)
    float X = 0.43395300f * lr + 0.37621900f * lg + 0.18982460f * lb;
    float Y = 0.21267100f * lr + 0.71516000f * lg + 0.07216900f * lb;
    float Z = 0.01775660f * lr + 0.10946970f * lg + 0.87270740f * lb;
    float fx = labf(X), fy = labf(Y), fz = labf(Z);
    L   = 116.0f * fy - 16.0f;
    a01 = (500.0f * (fx - fy) + 128.0f) * (1.0f / 255.0f);
    b01 = (200.0f * (fy - fz) + 128.0f) * (1.0f / 255.0f);
}

__global__ __launch_bounds__(TPB) void lab_norm_kernel(
        const float* __restrict__ x, float* __restrict__ out) {
    const int img = blockIdx.x;
    const float4* __restrict__ in4 = (const float4*)(x + (size_t)img * 49152);
    float4* __restrict__ out4 = (float4*)(out + (size_t)img * 49152);
    const int t = threadIdx.x;

    float4 v[12];
    float lmin = 3.4e38f, lmax = -3.4e38f;

#pragma unroll
    for (int g = 0; g < 4; ++g) {
        int idx = g * GROUP_STRIDE + t * 3;
        float4 A = in4[idx];
        float4 B = in4[idx + 1];
        float4 C = in4[idx + 2];
        float L0, a0, b0, L1, a1, b1, L2, a2, b2, L3, a3, b3;
        px(A.x, A.y, A.z, L0, a0, b0);
        px(A.w, B.x, B.y, L1, a1, b1);
        px(B.z, B.w, C.x, L2, a2, b2);
        px(C.y, C.z, C.w, L3, a3, b3);
        lmin = fminf(lmin, fminf(fminf(L0, L1), fminf(L2, L3)));
        lmax = fmaxf(lmax, fmaxf(fmaxf(L0, L1), fmaxf(L2, L3)));
        v[g * 3 + 0] = make_float4(L0, a0, b0, L1);
        v[g * 3 + 1] = make_float4(a1, b1, L2, a2);
        v[g * 3 + 2] = make_float4(b2, L3, a3, b3);
    }

    // wave (64-lane) butterfly reduce
#pragma unroll
    for (int m = 32; m >= 1; m >>= 1) {
        lmin = fminf(lmin, __shfl_xor(lmin, m, 64));
        lmax = fmaxf(lmax, __shfl_xor(lmax, m, 64));
    }

    __shared__ float smin[16], smax[16];
    int wid = t >> 6;
    if ((t & 63) == 0) { smin[wid] = lmin; smax[wid] = lmax; }
    __syncthreads();
    float bmin = smin[0], bmax = smax[0];
#pragma unroll
    for (int i = 1; i < 16; ++i) {
        bmin = fminf(bmin, smin[i]);
        bmax = fmaxf(bmax, smax[i]);
    }
    float s = 1.0f / (bmax - bmin);

#pragma unroll
    for (int g = 0; g < 4; ++g) {
        int idx = g * GROUP_STRIDE + t * 3;
        float4 o0 = v[g * 3 + 0];
        float4 o1 = v[g * 3 + 1];
        float4 o2 = v[g * 3 + 2];
        o0.x = (o0.x - bmin) * s;   // L0
        o0.w = (o0.w - bmin) * s;   // L1
        o1.z = (o1.z - bmin) * s;   // L2
        o2.y = (o2.y - bmin) * s;   // L3
        out4[idx]     = o0;
        out4[idx + 1] = o1;
        out4[idx + 2] = o2;
    }
}

extern "C" void kernel_launch(void* const* d_in, const int* in_sizes, int n_in,
                              void* d_out, int out_size, void* d_ws, size_t ws_size,
                              hipStream_t stream) {
    (void)in_sizes; (void)n_in; (void)out_size; (void)d_ws; (void)ws_size;
    const float* x = (const float*)d_in[0];
    float* out = (float*)d_out;
    // 512 images, one block each
    lab_norm_kernel<<<512, TPB, 0, stream>>>(x, out);
}

// Round 4
// 202.601 us; speedup vs baseline: 1.0282x; 1.0282x over previous
//
#include <hip/hip_runtime.h>

#define TPB 1024
// image = 128*128 px * 3 ch = 49152 floats = 12288 float4
// chunk = 3072 float4 = 12288 floats = 4096 pixels; 4 chunks per image

typedef __fp16 half2_t __attribute__((ext_vector_type(2)));

__device__ __forceinline__ float fexp2(float x) { return __builtin_amdgcn_exp2f(x); }
__device__ __forceinline__ float flog2(float x) { return __builtin_amdgcn_logf(x); }

__device__ __forceinline__ float s2lin(float c) {
    // inverse sRGB gamma; c in [0,1]
    float p = fexp2(flog2((c + 0.055f) * (1.0f / 1.055f)) * 2.4f);
    float l = c * (1.0f / 12.92f);
    return c > 0.04045f ? p : l;
}

__device__ __forceinline__ float labf(float t) {
    // t >= 0; log2(0)=-inf -> exp2 -> 0, discarded by select
    float p = fexp2(flog2(t) * (1.0f / 3.0f));
    float l = 7.787f * t + (16.0f / 116.0f);
    return t > 0.008856f ? p : l;
}

__device__ __forceinline__ void px(float r, float g, float b,
                                   float& L, float& a01, float& b01) {
    float lr = s2lin(r), lg = s2lin(g), lb = s2lin(b);
    // RGB2XYZ rows pre-divided by D65 white (0.95047, 1.0, 1.08883)
    float X = 0.43395300f * lr + 0.37621900f * lg + 0.18982460f * lb;
    float Y = 0.21267100f * lr + 0.71516000f * lg + 0.07216900f * lb;
    float Z = 0.01775660f * lr + 0.10946970f * lg + 0.87270740f * lb;
    float fx = labf(X), fy = labf(Y), fz = labf(Z);
    L   = 116.0f * fy - 16.0f;
    a01 = (500.0f * (fx - fy) + 128.0f) * (1.0f / 255.0f);
    b01 = (200.0f * (fy - fz) + 128.0f) * (1.0f / 255.0f);
}

__global__ __launch_bounds__(TPB, 8) void lab_norm_kernel(
        const float* __restrict__ x, float* __restrict__ out) {
    __shared__ float lds[12288];     // 48 KB chunk buffer
    __shared__ float smin[16], smax[16];

    const int img = blockIdx.x;
    const size_t ibase = (size_t)img * 49152;
    const int t = threadIdx.x;
    float4* const l4 = (float4*)lds;

    float   Lr[16];   // raw L per pixel (f32: min-max rescale amplifies error)
    half2_t AB[16];   // packed (a01,b01) f16 — 16 VGPRs instead of 32
    float lmin = 3.4e38f, lmax = -3.4e38f;

    // ---- Phase A: stage chunk -> LDS (unit-stride), compute Lab per pixel ----
#pragma unroll
    for (int g = 0; g < 4; ++g) {
        const float4* __restrict__ in4 = (const float4*)(x + ibase) + g * 3072;
        l4[t]        = in4[t];
        l4[t + 1024] = in4[t + 1024];
        l4[t + 2048] = in4[t + 2048];
        __syncthreads();
#pragma unroll
        for (int j = 0; j < 4; ++j) {
            int p3 = 3 * t + j * 3072;   // float index of pixel (t + j*1024)
            float r = lds[p3], gg = lds[p3 + 1], b = lds[p3 + 2];  // 2-way bank alias: free
            float L, a01, b01;
            px(r, gg, b, L, a01, b01);
            lmin = fminf(lmin, L);
            lmax = fmaxf(lmax, L);
            Lr[g * 4 + j] = L;
            AB[g * 4 + j] = __builtin_amdgcn_cvt_pkrtz(a01, b01);
        }
        __syncthreads();
    }

    // ---- Block reduction of lmin/lmax ----
#pragma unroll
    for (int m = 32; m >= 1; m >>= 1) {
        lmin = fminf(lmin, __shfl_xor(lmin, m, 64));
        lmax = fmaxf(lmax, __shfl_xor(lmax, m, 64));
    }
    int wid = t >> 6;
    if ((t & 63) == 0) { smin[wid] = lmin; smax[wid] = lmax; }
    __syncthreads();
    float bmin = smin[0], bmax = smax[0];
#pragma unroll
    for (int i = 1; i < 16; ++i) {
        bmin = fminf(bmin, smin[i]);
        bmax = fmaxf(bmax, smax[i]);
    }
    float s = 1.0f / (bmax - bmin);

    // ---- Phase B: results -> LDS, unit-stride store to global ----
#pragma unroll
    for (int g = 0; g < 4; ++g) {
#pragma unroll
        for (int j = 0; j < 4; ++j) {
            int p3 = 3 * t + j * 3072;
            half2_t hv = AB[g * 4 + j];
            lds[p3]     = (Lr[g * 4 + j] - bmin) * s;
            lds[p3 + 1] = (float)hv.x;
            lds[p3 + 2] = (float)hv.y;
        }
        __syncthreads();
        float4* __restrict__ o4 = (float4*)(out + ibase) + g * 3072;
        o4[t]        = l4[t];
        o4[t + 1024] = l4[t + 1024];
        o4[t + 2048] = l4[t + 2048];
        __syncthreads();
    }
}

extern "C" void kernel_launch(void* const* d_in, const int* in_sizes, int n_in,
                              void* d_out, int out_size, void* d_ws, size_t ws_size,
                              hipStream_t stream) {
    (void)in_sizes; (void)n_in; (void)out_size; (void)d_ws; (void)ws_size;
    const float* x = (const float*)d_in[0];
    float* out = (float*)d_out;
    lab_norm_kernel<<<512, TPB, 0, stream>>>(x, out);
}

// Round 5
// 198.521 us; speedup vs baseline: 1.0493x; 1.0205x over previous
//
#include <hip/hip_runtime.h>

#define TPB 1024
// image = 128*128 px * 3 ch = 49152 floats = 12288 float4
// chunk = 3072 float4 = 12288 floats = 4096 pixels; 4 chunks per image

typedef __fp16 half2_t __attribute__((ext_vector_type(2)));

__device__ __forceinline__ float fexp2(float x) { return __builtin_amdgcn_exp2f(x); }
__device__ __forceinline__ float flog2(float x) { return __builtin_amdgcn_logf(x); }

__device__ __forceinline__ float s2lin(float c) {
    float p = fexp2(flog2((c + 0.055f) * (1.0f / 1.055f)) * 2.4f);
    float l = c * (1.0f / 12.92f);
    return c > 0.04045f ? p : l;
}

__device__ __forceinline__ float labf(float t) {
    float p = fexp2(flog2(t) * (1.0f / 3.0f));
    float l = 7.787f * t + (16.0f / 116.0f);
    return t > 0.008856f ? p : l;
}

__device__ __forceinline__ void px(float r, float g, float b,
                                   float& L, float& a01, float& b01) {
    float lr = s2lin(r), lg = s2lin(g), lb = s2lin(b);
    // RGB2XYZ rows pre-divided by D65 white (0.95047, 1.0, 1.08883)
    float X = 0.43395300f * lr + 0.37621900f * lg + 0.18982460f * lb;
    float Y = 0.21267100f * lr + 0.71516000f * lg + 0.07216900f * lb;
    float Z = 0.01775660f * lr + 0.10946970f * lg + 0.87270740f * lb;
    float fx = labf(X), fy = labf(Y), fz = labf(Z);
    L   = 116.0f * fy - 16.0f;
    a01 = (500.0f * (fx - fy) + 128.0f) * (1.0f / 255.0f);
    b01 = (200.0f * (fy - fz) + 128.0f) * (1.0f / 255.0f);
}

__global__ __launch_bounds__(TPB, 8) void lab_norm_kernel(
        const float* __restrict__ x, float* __restrict__ out) {
    __shared__ float lds[12288];     // 48 KB chunk buffer
    __shared__ float smin[16], smax[16];

    const int img = blockIdx.x;
    const size_t ibase = (size_t)img * 49152;
    const int t = threadIdx.x;
    float4* const l4 = (float4*)lds;
    const float4* __restrict__ in4 = (const float4*)(x + ibase);

    float   Lr[16];
    half2_t AB[16];
    float lmin = 3.4e38f, lmax = -3.4e38f;

    // ---- Phase A: pipelined — prefetch chunk g+1 while computing chunk g ----
    float4 p0 = in4[t], p1 = in4[t + 1024], p2 = in4[t + 2048];

#pragma unroll
    for (int g = 0; g < 4; ++g) {
        l4[t]        = p0;
        l4[t + 1024] = p1;
        l4[t + 2048] = p2;
        __syncthreads();
        if (g < 3) {
            // issue next chunk's global loads NOW; vmcnt wait lands at the
            // top-of-loop LDS write, after ~160 VALU of compute below
            const float4* nx = in4 + (g + 1) * 3072;
            p0 = nx[t]; p1 = nx[t + 1024]; p2 = nx[t + 2048];
        }
#pragma unroll
        for (int j = 0; j < 4; ++j) {
            int p3 = 3 * t + j * 3072;   // 2-way bank alias: free
            float L, a01, b01;
            px(lds[p3], lds[p3 + 1], lds[p3 + 2], L, a01, b01);
            lmin = fminf(lmin, L);
            lmax = fmaxf(lmax, L);
            Lr[g * 4 + j] = L;
            AB[g * 4 + j] = __builtin_amdgcn_cvt_pkrtz(a01, b01);
        }
        __syncthreads();
    }

    // ---- Block reduction of lmin/lmax ----
#pragma unroll
    for (int m = 32; m >= 1; m >>= 1) {
        lmin = fminf(lmin, __shfl_xor(lmin, m, 64));
        lmax = fmaxf(lmax, __shfl_xor(lmax, m, 64));
    }
    int wid = t >> 6;
    if ((t & 63) == 0) { smin[wid] = lmin; smax[wid] = lmax; }
    __syncthreads();
    float bmin = smin[0], bmax = smax[0];
#pragma unroll
    for (int i = 1; i < 16; ++i) {
        bmin = fminf(bmin, smin[i]);
        bmax = fmaxf(bmax, smax[i]);
    }
    float s = 1.0f / (bmax - bmin);

    // ---- Phase B: pipelined — store chunk g while refilling LDS for g+1 ----
    float4* __restrict__ o4 = (float4*)(out + ibase);

    // prime: chunk 0 results -> LDS
#pragma unroll
    for (int j = 0; j < 4; ++j) {
        int p3 = 3 * t + j * 3072;
        half2_t hv = AB[j];
        lds[p3]     = (Lr[j] - bmin) * s;
        lds[p3 + 1] = (float)hv.x;
        lds[p3 + 2] = (float)hv.y;
    }
    __syncthreads();

#pragma unroll
    for (int g = 0; g < 4; ++g) {
        float4 r0 = l4[t], r1 = l4[t + 1024], r2 = l4[t + 2048];
        o4[g * 3072 + t]        = r0;   // fire-and-forget stores
        o4[g * 3072 + t + 1024] = r1;
        o4[g * 3072 + t + 2048] = r2;
        if (g < 3) {
            __syncthreads();            // all lanes' ds_reads done -> safe to overwrite
#pragma unroll
            for (int j = 0; j < 4; ++j) {
                int p3 = 3 * t + j * 3072;
                half2_t hv = AB[(g + 1) * 4 + j];
                lds[p3]     = (Lr[(g + 1) * 4 + j] - bmin) * s;
                lds[p3 + 1] = (float)hv.x;
                lds[p3 + 2] = (float)hv.y;
            }
            __syncthreads();
        }
    }
}

extern "C" void kernel_launch(void* const* d_in, const int* in_sizes, int n_in,
                              void* d_out, int out_size, void* d_ws, size_t ws_size,
                              hipStream_t stream) {
    (void)in_sizes; (void)n_in; (void)out_size; (void)d_ws; (void)ws_size;
    const float* x = (const float*)d_in[0];
    float* out = (float*)d_out;
    lab_norm_kernel<<<512, TPB, 0, stream>>>(x, out);
}

// Round 6
// 186.551 us; speedup vs baseline: 1.1167x; 1.0642x over previous
//
#include <hip/hip_runtime.h>

typedef unsigned int uint32;

__device__ __forceinline__ float fexp2(float x) { return __builtin_amdgcn_exp2f(x); }
__device__ __forceinline__ float flog2(float x) { return __builtin_amdgcn_logf(x); }

__device__ __forceinline__ float s2lin(float c) {
    float p = fexp2(flog2((c + 0.055f) * (1.0f / 1.055f)) * 2.4f);
    return c > 0.04045f ? p : c * (1.0f / 12.92f);
}

__device__ __forceinline__ float labf(float t) {
    float p = fexp2(flog2(t) * (1.0f / 3.0f));
    return t > 0.008856f ? p : 7.787f * t + (16.0f / 116.0f);
}

__device__ __forceinline__ void px(float r, float g, float b,
                                   float& L, float& a01, float& b01) {
    float lr = s2lin(r), lg = s2lin(g), lb = s2lin(b);
    // RGB2XYZ rows pre-divided by D65 white (0.95047, 1.0, 1.08883)
    float X = 0.43395300f * lr + 0.37621900f * lg + 0.18982460f * lb;
    float Y = 0.21267100f * lr + 0.71516000f * lg + 0.07216900f * lb;
    float Z = 0.01775660f * lr + 0.10946970f * lg + 0.87270740f * lb;
    float fx = labf(X), fy = labf(Y), fz = labf(Z);
    L   = 116.0f * fy - 16.0f;                              // L in [0,100]
    a01 = (500.0f * (fx - fy) + 128.0f) * (1.0f / 255.0f);  // in (0,1) for this matrix
    b01 = (200.0f * (fy - fz) + 128.0f) * (1.0f / 255.0f);  // in (0,1)
}

// ws layout: [0 .. 32 KB): header, 512 images x 8 subblocks x {min(L), min(100-L)} f32
//            [32 KB ..  ): 512*16384 packed px: u8 a | u8 b<<8 | f16 L<<16
#define HDR_U32 8192

// ---------------- fast path ----------------
__global__ __launch_bounds__(256) void k1_pack(const float* __restrict__ x,
                                               uint32* __restrict__ ws) {
    __shared__ float lds[6144];   // 24 KB = 2048 px
    __shared__ float sm[8];
    const int b = blockIdx.x, t = threadIdx.x;
    const int img = b >> 3, sub = b & 7;
    const size_t P = (size_t)img * 16384 + (size_t)sub * 2048;
    const float4* __restrict__ in4 =
        (const float4*)x + (size_t)img * 12288 + (size_t)sub * 1536;
    float4* l4 = (float4*)lds;
#pragma unroll
    for (int j = 0; j < 6; ++j) l4[t + j * 256] = in4[t + j * 256];
    __syncthreads();

    uint32* __restrict__ wpx = ws + HDR_U32 + P;
    float m1 = 3.4e38f, m2 = 3.4e38f;   // min(L), min(100-L)
#pragma unroll
    for (int j = 0; j < 8; ++j) {
        int p = t + (j << 8);
        float L, a01, b01;
        px(lds[3 * p], lds[3 * p + 1], lds[3 * p + 2], L, a01, b01);  // 2-way bank: free
        m1 = fminf(m1, L);
        m2 = fminf(m2, 100.0f - L);
        uint32 au = (uint32)(a01 * 255.0f + 0.5f);
        uint32 bu = (uint32)(b01 * 255.0f + 0.5f);
        unsigned short hb = __builtin_bit_cast(unsigned short, (_Float16)L);
        wpx[p] = au | (bu << 8) | ((uint32)hb << 16);   // unit-stride u32 store
    }
#pragma unroll
    for (int m = 32; m; m >>= 1) {
        m1 = fminf(m1, __shfl_xor(m1, m, 64));
        m2 = fminf(m2, __shfl_xor(m2, m, 64));
    }
    if ((t & 63) == 0) { sm[(t >> 6) * 2] = m1; sm[(t >> 6) * 2 + 1] = m2; }
    __syncthreads();
    if (t == 0) {
        float a = fminf(fminf(sm[0], sm[2]), fminf(sm[4], sm[6]));
        float c = fminf(fminf(sm[1], sm[3]), fminf(sm[5], sm[7]));
        float* hdr = (float*)ws;
        hdr[(img * 8 + sub) * 2]     = a;
        hdr[(img * 8 + sub) * 2 + 1] = c;
    }
}

__global__ __launch_bounds__(256) void k2_unpack(const uint32* __restrict__ ws,
                                                 float* __restrict__ out) {
    __shared__ float lds[6144];
    const int b = blockIdx.x, t = threadIdx.x;
    const int img = b >> 3, sub = b & 7;
    const size_t P = (size_t)img * 16384 + (size_t)sub * 2048;

    const float* hdr = (const float*)ws + (size_t)img * 16;
    float Lmin = 3.4e38f, m2 = 3.4e38f;
#pragma unroll
    for (int i = 0; i < 8; ++i) {
        Lmin = fminf(Lmin, hdr[2 * i]);
        m2   = fminf(m2, hdr[2 * i + 1]);
    }
    float s = 1.0f / ((100.0f - m2) - Lmin);

    const uint32* __restrict__ wpx = ws + HDR_U32 + P;
#pragma unroll
    for (int j = 0; j < 8; ++j) {
        int p = t + (j << 8);
        uint32 v = wpx[p];
        float a01 = (float)(v & 255u) * (1.0f / 255.0f);
        float b01 = (float)((v >> 8) & 255u) * (1.0f / 255.0f);
        float L = (float)__builtin_bit_cast(_Float16, (unsigned short)(v >> 16));
        lds[3 * p]     = (L - Lmin) * s;
        lds[3 * p + 1] = a01;
        lds[3 * p + 2] = b01;
    }
    __syncthreads();
    float4* l4 = (float4*)lds;
    float4* __restrict__ o4 =
        (float4*)out + (size_t)img * 12288 + (size_t)sub * 1536;
#pragma unroll
    for (int j = 0; j < 6; ++j) o4[t + j * 256] = l4[t + j * 256];
}

// ---------------- fallback path (ws too small for packed px) ----------------
__global__ __launch_bounds__(256) void k1_raw(const float* __restrict__ x,
                                              float* __restrict__ out,
                                              float* __restrict__ hdr) {
    __shared__ float lds[6144];
    __shared__ float sm[8];
    const int b = blockIdx.x, t = threadIdx.x;
    const int img = b >> 3, sub = b & 7;
    const float4* __restrict__ in4 =
        (const float4*)x + (size_t)img * 12288 + (size_t)sub * 1536;
    float4* l4 = (float4*)lds;
#pragma unroll
    for (int j = 0; j < 6; ++j) l4[t + j * 256] = in4[t + j * 256];
    __syncthreads();
    float m1 = 3.4e38f, m2 = 3.4e38f;
#pragma unroll
    for (int j = 0; j < 8; ++j) {
        int p = t + (j << 8);
        float L, a01, b01;
        px(lds[3 * p], lds[3 * p + 1], lds[3 * p + 2], L, a01, b01);
        m1 = fminf(m1, L);
        m2 = fminf(m2, 100.0f - L);
        lds[3 * p] = L; lds[3 * p + 1] = a01; lds[3 * p + 2] = b01;  // own slots
    }
    __syncthreads();
    float4* __restrict__ o4 =
        (float4*)out + (size_t)img * 12288 + (size_t)sub * 1536;
#pragma unroll
    for (int j = 0; j < 6; ++j) o4[t + j * 256] = l4[t + j * 256];
#pragma unroll
    for (int m = 32; m; m >>= 1) {
        m1 = fminf(m1, __shfl_xor(m1, m, 64));
        m2 = fminf(m2, __shfl_xor(m2, m, 64));
    }
    if ((t & 63) == 0) { sm[(t >> 6) * 2] = m1; sm[(t >> 6) * 2 + 1] = m2; }
    __syncthreads();
    if (t == 0) {
        hdr[(img * 8 + sub) * 2] =
            fminf(fminf(sm[0], sm[2]), fminf(sm[4], sm[6]));
        hdr[(img * 8 + sub) * 2 + 1] =
            fminf(fminf(sm[1], sm[3]), fminf(sm[5], sm[7]));
    }
}

__global__ __launch_bounds__(256) void k2_rescale(float* __restrict__ out,
                                                  const float* __restrict__ hdr0) {
    const int b = blockIdx.x, t = threadIdx.x;
    const int img = b >> 3, sub = b & 7;
    const float* hdr = hdr0 + (size_t)img * 16;
    float Lmin = 3.4e38f, m2 = 3.4e38f;
#pragma unroll
    for (int i = 0; i < 8; ++i) {
        Lmin = fminf(Lmin, hdr[2 * i]);
        m2   = fminf(m2, hdr[2 * i + 1]);
    }
    float s = 1.0f / ((100.0f - m2) - Lmin);
    float4* __restrict__ o4 =
        (float4*)out + (size_t)img * 12288 + (size_t)sub * 1536;
#pragma unroll
    for (int j = 0; j < 6; ++j) {
        int idx = t + j * 256;
        float4 v = o4[idx];
        int r = idx % 3;   // (idx+i)%3==0 -> component i is an L slot
        if (r == 0)      { v.x = (v.x - Lmin) * s; v.w = (v.w - Lmin) * s; }
        else if (r == 1) { v.z = (v.z - Lmin) * s; }
        else             { v.y = (v.y - Lmin) * s; }
        o4[idx] = v;
    }
}

extern "C" void kernel_launch(void* const* d_in, const int* in_sizes, int n_in,
                              void* d_out, int out_size, void* d_ws, size_t ws_size,
                              hipStream_t stream) {
    (void)in_sizes; (void)n_in; (void)out_size;
    const float* x = (const float*)d_in[0];
    float* out = (float*)d_out;
    const size_t need = 32768ull + 512ull * 16384ull * 4ull;  // header + packed px
    if (ws_size >= need) {
        k1_pack<<<4096, 256, 0, stream>>>(x, (uint32*)d_ws);
        k2_unpack<<<4096, 256, 0, stream>>>((const uint32*)d_ws, out);
    } else {
        k1_raw<<<4096, 256, 0, stream>>>(x, out, (float*)d_ws);
        k2_rescale<<<4096, 256, 0, stream>>>(out, (const float*)d_ws);
    }
}